// Round 1
// baseline (1695.503 us; speedup 1.0000x reference)
//
#include <hip/hip_runtime.h>

// NetG: seq2seq GRU (enc GRU -> +noise -> dec GRU -> FC head)
// B=512, T=256, H=256, D=3.
//
// Design: persistent-RNN. 32 blocks x 512 threads (8 waves, 2 waves/SIMD,
// __launch_bounds__(512,2) -> 256 VGPR budget). Each block owns 16 batch rows
// for the whole sequence. W_hh bf16 A-fragments live in 192 VGPRs/lane for the
// entire kernel. Per step: gh^T = W.h^T via mfma_f32_16x16x32_bf16, with a 9th
// K-step carrying [x0,x1,x2,1] so the input projection + biases ride the MFMA.
// n-gate keeps hn (+b_hh) and xn (+b_ih) in separate accumulators to honor
// PyTorch's n = tanh(xn + r*hn). h carried in fp32 in LDS; bf16 copy feeds the
// GEMM. Decoder streams h_t to ws (bf16) for a final projection kernel.

#define B_TOT 512
#define T_LEN 256
#define HID 256
#define IND 3
#define NBLK 32      // batch groups (512/16)
#define NBATCH 16    // batch rows per block (MFMA N)
#define NTHREADS 512 // 8 waves

typedef __attribute__((ext_vector_type(4))) float f32x4;
typedef __attribute__((ext_vector_type(8))) short shortx8;
typedef __attribute__((ext_vector_type(4))) unsigned short ushortx4;
typedef __attribute__((ext_vector_type(8))) unsigned short ushortx8;

// h row: 256 h | x0 x1 x2 1.0 | 4 zero pad  (stride 264 = 132 dwords -> 2-way
// max bank aliasing on b128 reads, which is free)
#define H_STRIDE 264
#define H_BUFSZ (NBATCH * H_STRIDE + 32)  // +32 slack for q>=1 overrun on k-step 8 (A=0 there)
#define HOLD_STRIDE 260                   // fp32 h, padded (+4) to break 256-stride conflicts

__device__ __forceinline__ unsigned short f2bf(float x) {
    unsigned u = __float_as_uint(x);
    u += 0x7FFF + ((u >> 16) & 1);   // RNE
    return (unsigned short)(u >> 16);
}
__device__ __forceinline__ float bf2f(unsigned short s) {
    return __uint_as_float(((unsigned)s) << 16);
}
__device__ __forceinline__ float sigmoidf_(float x) {
    return 1.0f / (1.0f + __expf(-x));
}
__device__ __forceinline__ float tanhf_(float x) {
    return 2.0f / (1.0f + __expf(-2.0f * x)) - 1.0f;
}

__global__ __launch_bounds__(NTHREADS, 2) void gru_persistent(
    const float* __restrict__ X,       // [512][256][3]
    const float* __restrict__ W_hh,    // [768][256], gate order r,z,n
    const float* __restrict__ W_ih,    // [768][3]
    const float* __restrict__ b_ih,    // [768]
    const float* __restrict__ b_hh,    // [768]
    const float* __restrict__ h_in,    // dec: [512][256] fp32 (enc final h); enc: null
    const float* __restrict__ noise,   // dec: [512][256]; enc: null
    float* __restrict__ h_out,         // enc: [512][256] fp32; dec: null
    unsigned short* __restrict__ Yout, // dec: [32][256][16][256] bf16; enc: null
    int is_dec)
{
    __shared__ unsigned short sh_h[2][H_BUFSZ];          // bf16 h + x-ext, double buffered
    __shared__ float sh_hold[NBATCH * HOLD_STRIDE];      // fp32-carried h (lane-private slots)
    __shared__ unsigned short sh_xfrag[64 * 64 * 4];     // x/bias A-frags: (kind*16+ht, lane, 4)

    const int tid  = threadIdx.x;
    const int g    = blockIdx.x;
    const int w    = tid >> 6;    // wave 0..7; owns hidden tiles {w, w+8}
    const int lane = tid & 63;
    const int c    = lane & 15;   // A-row (gate row) on input side; batch col on D side
    const int q    = lane >> 4;

    // ---- zero LDS (slack/pad regions must be 0 and stay 0) ----
    for (int i = tid; i < 2 * H_BUFSZ; i += NTHREADS) ((unsigned short*)sh_h)[i] = 0;
    for (int i = tid; i < NBATCH * HOLD_STRIDE; i += NTHREADS) sh_hold[i] = 0.0f;
    // sh_xfrag fully written below (every wave covers its 2 ht x 4 kinds x its 64 lanes)

    // ---- build x/bias A-fragments (only quad 0 carries data; k>=4 is zero) ----
    // kind 0: r-gate  [Wih0,Wih1,Wih2, b_ih+b_hh]
    // kind 1: z-gate  [Wih0,Wih1,Wih2, b_ih+b_hh]
    // kind 2: n-gate hidden bias [0,0,0, b_hh]
    // kind 3: n-gate x part      [Wih0,Wih1,Wih2, b_ih]
    #pragma unroll
    for (int hti = 0; hti < 2; ++hti) {
        int ht = w + hti * 8;
        #pragma unroll
        for (int kind = 0; kind < 4; ++kind) {
            unsigned short v0 = 0, v1 = 0, v2 = 0, v3 = 0;
            if (q == 0) {
                int gbase = (kind == 0) ? 0 : (kind == 1) ? 256 : 512;
                int row = gbase + ht * 16 + c;
                if (kind == 0 || kind == 1) {
                    v0 = f2bf(W_ih[row * 3 + 0]);
                    v1 = f2bf(W_ih[row * 3 + 1]);
                    v2 = f2bf(W_ih[row * 3 + 2]);
                    v3 = f2bf(b_ih[row] + b_hh[row]);
                } else if (kind == 2) {
                    v3 = f2bf(b_hh[row]);
                } else {
                    v0 = f2bf(W_ih[row * 3 + 0]);
                    v1 = f2bf(W_ih[row * 3 + 1]);
                    v2 = f2bf(W_ih[row * 3 + 2]);
                    v3 = f2bf(b_ih[row]);
                }
            }
            ushortx4 vv = {v0, v1, v2, v3};
            *(ushortx4*)&sh_xfrag[((kind * 16 + ht) * 64 + lane) * 4] = vv;
        }
    }

    // ---- load W_hh A-fragments into registers (resident whole kernel) ----
    // A[m=lane&15][k=q*8+j] -> lane holds W_hh[gbase+ht*16+c][kstep*32+q*8 .. +7]
    shortx8 Wf[2][3][8];
    #pragma unroll
    for (int hti = 0; hti < 2; ++hti) {
        int ht = w + hti * 8;
        #pragma unroll
        for (int gg = 0; gg < 3; ++gg) {
            int row = gg * 256 + ht * 16 + c;
            const float* wp = W_hh + row * 256 + q * 8;
            #pragma unroll
            for (int k = 0; k < 8; ++k) {
                const f32x4* p = (const f32x4*)(wp + k * 32);
                f32x4 f0 = p[0];
                f32x4 f1 = p[1];
                shortx8 a;
                a[0] = (short)f2bf(f0[0]); a[1] = (short)f2bf(f0[1]);
                a[2] = (short)f2bf(f0[2]); a[3] = (short)f2bf(f0[3]);
                a[4] = (short)f2bf(f1[0]); a[5] = (short)f2bf(f1[1]);
                a[6] = (short)f2bf(f1[2]); a[7] = (short)f2bf(f1[3]);
                Wf[hti][gg][k] = a;
            }
        }
    }

    // ---- init h (epilogue lane owns batch c, dims ht*16+q*4..+3) ----
    #pragma unroll
    for (int hti = 0; hti < 2; ++hti) {
        int ht = w + hti * 8;
        int dim0 = ht * 16 + q * 4;
        f32x4 hv = {0.0f, 0.0f, 0.0f, 0.0f};
        if (is_dec) {
            int b = g * NBATCH + c;
            f32x4 h0 = *(const f32x4*)(h_in + b * HID + dim0);
            f32x4 nz = *(const f32x4*)(noise + b * HID + dim0);
            hv = h0 + nz;
        }
        *(f32x4*)&sh_hold[c * HOLD_STRIDE + dim0] = hv;
        ushortx4 hb16 = {f2bf(hv[0]), f2bf(hv[1]), f2bf(hv[2]), f2bf(hv[3])};
        *(ushortx4*)&sh_h[0][c * H_STRIDE + dim0] = hb16;
    }
    // x-ext for step 0: enc -> X[:,0]; dec -> zeros (right-shifted input)
    if (tid < NBATCH) {
        float x0 = 0.0f, x1 = 0.0f, x2 = 0.0f;
        if (!is_dec) {
            const float* xp = X + (size_t)(g * NBATCH + tid) * (T_LEN * IND);
            x0 = xp[0]; x1 = xp[1]; x2 = xp[2];
        }
        ushortx4 xe = {f2bf(x0), f2bf(x1), f2bf(x2), f2bf(1.0f)};
        *(ushortx4*)&sh_h[0][tid * H_STRIDE + 256] = xe;
    }
    __syncthreads();

    // ---- recurrence ----
    for (int t = 0; t < T_LEN; ++t) {
        const unsigned short* hb = sh_h[t & 1];        // h_t
        unsigned short* hn = sh_h[(t + 1) & 1];        // h_{t+1} (written by epilogue)

        // stream h_t (= decoder output of step t-1) to global; overlaps MFMA
        if (is_dec && t >= 1) {
            int row = tid >> 5, col8 = (tid & 31) * 8;
            ushortx8 v = *(const ushortx8*)(hb + row * H_STRIDE + col8);
            *(ushortx8*)(Yout + (((size_t)g * T_LEN + (t - 1)) * NBATCH + row) * HID + col8) = v;
        }

        f32x4 acc[2][4];  // [hti][r, z, nh, nx]
        #pragma unroll
        for (int hti = 0; hti < 2; ++hti)
            #pragma unroll
            for (int kk = 0; kk < 4; ++kk) {
                f32x4 z4 = {0.0f, 0.0f, 0.0f, 0.0f};
                acc[hti][kk] = z4;
            }

        const unsigned short* brow = hb + c * H_STRIDE;
        #pragma unroll
        for (int k = 0; k < 8; ++k) {
            shortx8 bf = *(const shortx8*)(brow + k * 32 + q * 8);  // B[k][n=batch]
            #pragma unroll
            for (int hti = 0; hti < 2; ++hti) {
                acc[hti][0] = __builtin_amdgcn_mfma_f32_16x16x32_bf16(Wf[hti][0][k], bf, acc[hti][0], 0, 0, 0);
                acc[hti][1] = __builtin_amdgcn_mfma_f32_16x16x32_bf16(Wf[hti][1][k], bf, acc[hti][1], 0, 0, 0);
                acc[hti][2] = __builtin_amdgcn_mfma_f32_16x16x32_bf16(Wf[hti][2][k], bf, acc[hti][2], 0, 0, 0);
            }
        }
        // 9th K-step: B cols 256..263 = [x0,x1,x2,1,0,0,0,0]; A from sh_xfrag
        {
            shortx8 bx = *(const shortx8*)(brow + 256 + q * 8);
            #pragma unroll
            for (int hti = 0; hti < 2; ++hti) {
                int ht = w + hti * 8;
                #pragma unroll
                for (int kind = 0; kind < 4; ++kind) {
                    ushortx4 xa = *(const ushortx4*)&sh_xfrag[((kind * 16 + ht) * 64 + lane) * 4];
                    shortx8 a = {(short)xa[0], (short)xa[1], (short)xa[2], (short)xa[3],
                                 (short)0, (short)0, (short)0, (short)0};
                    acc[hti][kind] = __builtin_amdgcn_mfma_f32_16x16x32_bf16(a, bx, acc[hti][kind], 0, 0, 0);
                }
            }
        }

        // ---- epilogue: D[row=q*4+r][col=batch=c]; fp32-carried h ----
        #pragma unroll
        for (int hti = 0; hti < 2; ++hti) {
            int ht = w + hti * 8;
            int dim0 = ht * 16 + q * 4;
            f32x4 hv = *(const f32x4*)&sh_hold[c * HOLD_STRIDE + dim0];
            f32x4 ho;
            #pragma unroll
            for (int r = 0; r < 4; ++r) {
                float rr = sigmoidf_(acc[hti][0][r]);
                float zz = sigmoidf_(acc[hti][1][r]);
                float nn = tanhf_(acc[hti][3][r] + rr * acc[hti][2][r]);
                ho[r] = nn + zz * (hv[r] - nn);
            }
            *(f32x4*)&sh_hold[c * HOLD_STRIDE + dim0] = ho;
            ushortx4 hb16 = {f2bf(ho[0]), f2bf(ho[1]), f2bf(ho[2]), f2bf(ho[3])};
            *(ushortx4*)(hn + c * H_STRIDE + dim0) = hb16;
        }
        // x-ext for step t+1: enc -> X[:,t+1]; dec -> X[:,t] (shifted)
        if (tid < NBATCH) {
            float x0 = 0.0f, x1 = 0.0f, x2 = 0.0f;
            int ts = is_dec ? t : (t + 1);
            if (ts < T_LEN) {
                const float* xp = X + ((size_t)(g * NBATCH + tid) * T_LEN + ts) * IND;
                x0 = xp[0]; x1 = xp[1]; x2 = xp[2];
            }
            ushortx4 xe = {f2bf(x0), f2bf(x1), f2bf(x2), f2bf(1.0f)};
            *(ushortx4*)(hn + tid * H_STRIDE + 256) = xe;
        }
        __syncthreads();
    }

    if (is_dec) {
        // flush Y[:,255] = h_256 (sits in sh_h[0] since T is even)
        int row = tid >> 5, col8 = (tid & 31) * 8;
        ushortx8 v = *(const ushortx8*)(sh_h[0] + row * H_STRIDE + col8);
        *(ushortx8*)(Yout + (((size_t)g * T_LEN + 255) * NBATCH + row) * HID + col8) = v;
    } else {
        // encoder: write final fp32 h
        #pragma unroll
        for (int hti = 0; hti < 2; ++hti) {
            int ht = w + hti * 8;
            int dim0 = ht * 16 + q * 4;
            f32x4 hv = *(const f32x4*)&sh_hold[c * HOLD_STRIDE + dim0];
            *(f32x4*)(h_out + (size_t)(g * NBATCH + c) * HID + dim0) = hv;
        }
    }
}

// out[b][t][d] = sum_h Y[g][t][b16][h] * W_fc[d][h] + b_fc[d]
__global__ __launch_bounds__(256) void proj_kernel(
    const unsigned short* __restrict__ Y, const float* __restrict__ W_fc,
    const float* __restrict__ b_fc, float* __restrict__ out)
{
    int row = blockIdx.x * 256 + threadIdx.x;  // ((g*T + t)*16 + b16)
    int b16 = row & 15;
    int gt = row >> 4;
    int t = gt & (T_LEN - 1);
    int g = gt >> 8;
    const unsigned short* y = Y + (size_t)row * HID;
    float a0 = b_fc[0], a1 = b_fc[1], a2 = b_fc[2];
    #pragma unroll 4
    for (int k8 = 0; k8 < 32; ++k8) {
        ushortx8 v = *(const ushortx8*)(y + k8 * 8);
        #pragma unroll
        for (int j = 0; j < 8; ++j) {
            float f = bf2f(v[j]);
            int k = k8 * 8 + j;
            a0 += f * W_fc[k];          // W_fc rows are uniform -> scalar loads
            a1 += f * W_fc[256 + k];
            a2 += f * W_fc[512 + k];
        }
    }
    int batch = g * NBATCH + b16;
    float* o = out + ((size_t)batch * T_LEN + t) * IND;
    o[0] = a0; o[1] = a1; o[2] = a2;
}

extern "C" void kernel_launch(void* const* d_in, const int* in_sizes, int n_in,
                              void* d_out, int out_size, void* d_ws, size_t ws_size,
                              hipStream_t stream)
{
    const float* X_p      = (const float*)d_in[0];
    const float* X_f      = (const float*)d_in[1];
    const float* noise    = (const float*)d_in[2];
    const float* W_ih_enc = (const float*)d_in[3];
    const float* W_hh_enc = (const float*)d_in[4];
    const float* b_ih_enc = (const float*)d_in[5];
    const float* b_hh_enc = (const float*)d_in[6];
    const float* W_ih_dec = (const float*)d_in[7];
    const float* W_hh_dec = (const float*)d_in[8];
    const float* b_ih_dec = (const float*)d_in[9];
    const float* b_hh_dec = (const float*)d_in[10];
    const float* W_fc     = (const float*)d_in[11];
    const float* b_fc     = (const float*)d_in[12];

    // ws: [0, 512KB) fp32 encoder final h; then 67MB bf16 decoder outputs
    float* h_enc = (float*)d_ws;
    unsigned short* Yws = (unsigned short*)((char*)d_ws + (size_t)B_TOT * HID * 4);

    hipLaunchKernelGGL(gru_persistent, dim3(NBLK), dim3(NTHREADS), 0, stream,
        X_p, W_hh_enc, W_ih_enc, b_ih_enc, b_hh_enc,
        (const float*)nullptr, (const float*)nullptr, h_enc,
        (unsigned short*)nullptr, 0);

    hipLaunchKernelGGL(gru_persistent, dim3(NBLK), dim3(NTHREADS), 0, stream,
        X_f, W_hh_dec, W_ih_dec, b_ih_dec, b_hh_dec,
        h_enc, noise, (float*)nullptr, Yws, 1);

    hipLaunchKernelGGL(proj_kernel, dim3((B_TOT * T_LEN) / 256), dim3(256), 0, stream,
        Yws, W_fc, b_fc, (float*)d_out);
}

// Round 2
// 1250.063 us; speedup vs baseline: 1.3563x; 1.3563x over previous
//
#include <hip/hip_runtime.h>

// NetG: seq2seq GRU (enc GRU -> +noise -> dec GRU -> FC head)
// B=512, T=256, H=256, D=3.
//
// Persistent-RNN: 32 blocks x 512 threads (8 waves, 2/SIMD, hard 256-reg cap).
// Each block owns 16 batch rows for the whole sequence. W_hh bf16 A-frags
// resident in 192 regs/lane. Per step: gh = W.h^T via mfma_f32_16x16x32_bf16
// (8 K-steps) + a 9th K-step carrying [x0,x1,x2,1] folding input projection
// and biases. h carried fp32 in REGISTERS (lane-private); bf16 copy in LDS is
// the MFMA B operand.
//
// LDS h layout: row stride 256 shorts (512 B), 16B-block swizzle j^(c&7) ->
// every 8-lane phase of a b128 read hits a bank-permutation: conflict-free.
// X staged in LDS once (bf16, decoder right-shift baked in) -> no global
// loads in the step loop. x/bias A-frags: 2 conflict-free b128 LDS reads.

#define B_TOT 512
#define T_LEN 256
#define HID 256
#define NBATCH 16
#define NTHREADS 512
#define NBLK 32
#define XROW 1032   // shorts per batch row of staged X (256*4 + 8 pad)

typedef __attribute__((ext_vector_type(4))) float f32x4;
typedef __attribute__((ext_vector_type(8))) short shortx8;
typedef __attribute__((ext_vector_type(4))) unsigned short ushortx4;
typedef __attribute__((ext_vector_type(8))) unsigned short ushortx8;

__device__ __forceinline__ unsigned short f2bf(float x) {
    unsigned u = __float_as_uint(x);
    u += 0x7FFF + ((u >> 16) & 1);   // RNE
    return (unsigned short)(u >> 16);
}
__device__ __forceinline__ float bf2f(unsigned short s) {
    return __uint_as_float(((unsigned)s) << 16);
}
__device__ __forceinline__ float fastrcp(float x) {
#if __has_builtin(__builtin_amdgcn_rcpf)
    return __builtin_amdgcn_rcpf(x);
#else
    return 1.0f / x;
#endif
}
__device__ __forceinline__ float sigmoid_(float x) {
    return fastrcp(1.0f + __expf(-x));
}
__device__ __forceinline__ float tanh_(float x) {
    return 2.0f * fastrcp(1.0f + __expf(-2.0f * x)) - 1.0f;
}

template<int IS_DEC>
__global__ __launch_bounds__(NTHREADS, 2) void gru_persistent(
    const float* __restrict__ X,       // [512][256][3]
    const float* __restrict__ W_hh,    // [768][256] gates r,z,n
    const float* __restrict__ W_ih,    // [768][3]
    const float* __restrict__ b_ih,    // [768]
    const float* __restrict__ b_hh,    // [768]
    const float* __restrict__ h_in,    // dec: [512][256] fp32; enc: null
    const float* __restrict__ noise,   // dec: [512][256]; enc: null
    float* __restrict__ h_out,         // enc: [512][256] fp32; dec: null
    unsigned short* __restrict__ Yout) // dec: [32][256][16][256] bf16
{
    __shared__ unsigned short sh_h[2][NBATCH * HID];        // swizzled bf16 h
    __shared__ unsigned short sh_x[NBATCH * XROW];          // staged x (+1.0)
    __shared__ unsigned short sh_xf01[NBATCH * NBATCH * 8]; // [ht][c]{r|z}
    __shared__ unsigned short sh_xf23[NBATCH * NBATCH * 8]; // [ht][c]{nh|nx}

    const int tid  = threadIdx.x;
    const int g    = blockIdx.x;
    const int w    = tid >> 6;    // wave; owns hidden tiles {w, w+8}
    const int lane = tid & 63;
    const int c    = lane & 15;   // A row / B col (batch) / D col
    const int q    = lane >> 4;
    const int cx   = c & 7;

    // ---- stage X into LDS (bf16, shift baked in; 4th slot = 1.0 for bias) ----
    for (int idx = tid; idx < NBATCH * T_LEN; idx += NTHREADS) {
        int cc = idx >> 8, t = idx & 255;
        int ts = IS_DEC ? (t - 1) : t;
        float x0 = 0.0f, x1 = 0.0f, x2 = 0.0f;
        if (ts >= 0) {
            const float* xp = X + ((size_t)(g * NBATCH + cc) * T_LEN + ts) * 3;
            x0 = xp[0]; x1 = xp[1]; x2 = xp[2];
        }
        ushortx4 v = {f2bf(x0), f2bf(x1), f2bf(x2), (unsigned short)0x3F80};
        *(ushortx4*)&sh_x[cc * XROW + t * 4] = v;
    }

    // ---- x/bias A-frags -> LDS (per (ht,c); only K-slots 0..3 of each kind) ----
    if (q == 0) {
        #pragma unroll
        for (int hti = 0; hti < 2; ++hti) {
            int ht = w + hti * 8;
            int rr = ht * 16 + c;
            int rowr = rr, rowz = 256 + rr, rown = 512 + rr;
            ushortx8 v01 = {
                f2bf(W_ih[rowr * 3 + 0]), f2bf(W_ih[rowr * 3 + 1]),
                f2bf(W_ih[rowr * 3 + 2]), f2bf(b_ih[rowr] + b_hh[rowr]),
                f2bf(W_ih[rowz * 3 + 0]), f2bf(W_ih[rowz * 3 + 1]),
                f2bf(W_ih[rowz * 3 + 2]), f2bf(b_ih[rowz] + b_hh[rowz])};
            ushortx8 v23 = {
                (unsigned short)0, (unsigned short)0, (unsigned short)0,
                f2bf(b_hh[rown]),
                f2bf(W_ih[rown * 3 + 0]), f2bf(W_ih[rown * 3 + 1]),
                f2bf(W_ih[rown * 3 + 2]), f2bf(b_ih[rown])};
            *(ushortx8*)&sh_xf01[(ht * 16 + c) * 8] = v01;
            *(ushortx8*)&sh_xf23[(ht * 16 + c) * 8] = v23;
        }
    }

    // ---- W_hh A-frags into registers (resident whole kernel) ----
    // A[m=c][k=q*8+j] -> lane holds W_hh[gbase+ht*16+c][kstep*32+q*8 .. +7]
    shortx8 Wf[2][3][8];
    #pragma unroll
    for (int hti = 0; hti < 2; ++hti) {
        int ht = w + hti * 8;
        #pragma unroll
        for (int gg = 0; gg < 3; ++gg) {
            int row = gg * 256 + ht * 16 + c;
            const float* wp = W_hh + row * 256 + q * 8;
            #pragma unroll
            for (int k = 0; k < 8; ++k) {
                const f32x4* p = (const f32x4*)(wp + k * 32);
                f32x4 f0 = p[0];
                f32x4 f1 = p[1];
                shortx8 a;
                a[0] = (short)f2bf(f0[0]); a[1] = (short)f2bf(f0[1]);
                a[2] = (short)f2bf(f0[2]); a[3] = (short)f2bf(f0[3]);
                a[4] = (short)f2bf(f1[0]); a[5] = (short)f2bf(f1[1]);
                a[6] = (short)f2bf(f1[2]); a[7] = (short)f2bf(f1[3]);
                Wf[hti][gg][k] = a;
            }
        }
    }

    // ---- epilogue write offsets (swizzled), loop-invariant ----
    int woff[2];
    #pragma unroll
    for (int hti = 0; hti < 2; ++hti) {
        int ht = w + hti * 8;
        woff[hti] = c * HID + (((2 * ht + (q >> 1)) ^ cx) << 3) + ((q & 1) << 2);
    }

    // ---- init h: fp32 in regs; bf16 copy to sh_h[0] ----
    f32x4 hold[2];
    #pragma unroll
    for (int hti = 0; hti < 2; ++hti) {
        int ht = w + hti * 8;
        int dim0 = ht * 16 + q * 4;
        f32x4 hv = {0.0f, 0.0f, 0.0f, 0.0f};
        if (IS_DEC) {
            int b = g * NBATCH + c;
            f32x4 h0 = *(const f32x4*)(h_in + (size_t)b * HID + dim0);
            f32x4 nz = *(const f32x4*)(noise + (size_t)b * HID + dim0);
            hv = h0 + nz;
        }
        hold[hti] = hv;
        ushortx4 hb16 = {f2bf(hv[0]), f2bf(hv[1]), f2bf(hv[2]), f2bf(hv[3])};
        *(ushortx4*)&sh_h[0][woff[hti]] = hb16;
    }
    __syncthreads();

    const shortx8 zero8 = {0, 0, 0, 0, 0, 0, 0, 0};
    const unsigned short* xrow = sh_x + c * XROW;

    // ---- recurrence ----
    for (int t = 0; t < T_LEN; ++t) {
        const unsigned short* hb = sh_h[t & 1];
        unsigned short* hn = sh_h[(t + 1) & 1];

        // decoder: stream h_t (= y_{t-1}) to global; overlaps MFMA
        if (IS_DEC && t >= 1) {
            int row = tid >> 5, jl = tid & 31;
            ushortx8 v = *(const ushortx8*)(hb + row * HID + ((jl ^ (row & 7)) << 3));
            *(ushortx8*)(Yout + (((size_t)g * T_LEN + (t - 1)) * NBATCH + row) * HID + jl * 8) = v;
        }

        f32x4 acc[2][4];  // [hti][r, z, nh, nx]
        #pragma unroll
        for (int hti = 0; hti < 2; ++hti)
            #pragma unroll
            for (int kk = 0; kk < 4; ++kk) {
                f32x4 z4 = {0.0f, 0.0f, 0.0f, 0.0f};
                acc[hti][kk] = z4;
            }

        const unsigned short* brow = hb + c * HID;
        #pragma unroll
        for (int k = 0; k < 8; ++k) {
            shortx8 bf = *(const shortx8*)(brow + (((4 * k + q) ^ cx) << 3));
            #pragma unroll
            for (int hti = 0; hti < 2; ++hti) {
                acc[hti][0] = __builtin_amdgcn_mfma_f32_16x16x32_bf16(Wf[hti][0][k], bf, acc[hti][0], 0, 0, 0);
                acc[hti][1] = __builtin_amdgcn_mfma_f32_16x16x32_bf16(Wf[hti][1][k], bf, acc[hti][1], 0, 0, 0);
                acc[hti][2] = __builtin_amdgcn_mfma_f32_16x16x32_bf16(Wf[hti][2][k], bf, acc[hti][2], 0, 0, 0);
            }
        }

        // 9th K-step: B rows 0..3 = [x0,x1,x2,1] (q=0 lanes), rest zero
        {
            ushortx4 xv = *(const ushortx4*)(xrow + t * 4);
            shortx8 bx = {(short)xv[0], (short)xv[1], (short)xv[2], (short)xv[3],
                          (short)0, (short)0, (short)0, (short)0};
            #pragma unroll
            for (int hti = 0; hti < 2; ++hti) {
                int ht = w + hti * 8;
                ushortx8 p01 = *(const ushortx8*)&sh_xf01[(ht * 16 + c) * 8];
                ushortx8 p23 = *(const ushortx8*)&sh_xf23[(ht * 16 + c) * 8];
                shortx8 a0 = (q == 0) ? shortx8{(short)p01[0], (short)p01[1], (short)p01[2], (short)p01[3], 0, 0, 0, 0} : zero8;
                shortx8 a1 = (q == 0) ? shortx8{(short)p01[4], (short)p01[5], (short)p01[6], (short)p01[7], 0, 0, 0, 0} : zero8;
                shortx8 a2 = (q == 0) ? shortx8{(short)p23[0], (short)p23[1], (short)p23[2], (short)p23[3], 0, 0, 0, 0} : zero8;
                shortx8 a3 = (q == 0) ? shortx8{(short)p23[4], (short)p23[5], (short)p23[6], (short)p23[7], 0, 0, 0, 0} : zero8;
                acc[hti][0] = __builtin_amdgcn_mfma_f32_16x16x32_bf16(a0, bx, acc[hti][0], 0, 0, 0);
                acc[hti][1] = __builtin_amdgcn_mfma_f32_16x16x32_bf16(a1, bx, acc[hti][1], 0, 0, 0);
                acc[hti][2] = __builtin_amdgcn_mfma_f32_16x16x32_bf16(a2, bx, acc[hti][2], 0, 0, 0);
                acc[hti][3] = __builtin_amdgcn_mfma_f32_16x16x32_bf16(a3, bx, acc[hti][3], 0, 0, 0);
            }
        }

        // ---- epilogue: D[row=q*4+r][col=c]; h carried fp32 in regs ----
        #pragma unroll
        for (int hti = 0; hti < 2; ++hti) {
            f32x4 hv = hold[hti];
            f32x4 ho;
            #pragma unroll
            for (int r = 0; r < 4; ++r) {
                float rr = sigmoid_(acc[hti][0][r]);
                float zz = sigmoid_(acc[hti][1][r]);
                float nn = tanh_(acc[hti][3][r] + rr * acc[hti][2][r]);
                ho[r] = nn + zz * (hv[r] - nn);
            }
            hold[hti] = ho;
            ushortx4 hb16 = {f2bf(ho[0]), f2bf(ho[1]), f2bf(ho[2]), f2bf(ho[3])};
            *(ushortx4*)(hn + woff[hti]) = hb16;
        }
        __syncthreads();
    }

    if (IS_DEC) {
        // flush Y[:,255] = h_256 (in sh_h[0], T even)
        int row = tid >> 5, jl = tid & 31;
        ushortx8 v = *(const ushortx8*)(&sh_h[0][0] + row * HID + ((jl ^ (row & 7)) << 3));
        *(ushortx8*)(Yout + (((size_t)g * T_LEN + 255) * NBATCH + row) * HID + jl * 8) = v;
    } else {
        #pragma unroll
        for (int hti = 0; hti < 2; ++hti) {
            int ht = w + hti * 8;
            int dim0 = ht * 16 + q * 4;
            *(f32x4*)(h_out + (size_t)(g * NBATCH + c) * HID + dim0) = hold[hti];
        }
    }
}

// out[b][t][d] = sum_h Y[g][t][b16][h] * W_fc[d][h] + b_fc[d]
__global__ __launch_bounds__(256) void proj_kernel(
    const unsigned short* __restrict__ Y, const float* __restrict__ W_fc,
    const float* __restrict__ b_fc, float* __restrict__ out)
{
    int row = blockIdx.x * 256 + threadIdx.x;  // ((g*T + t)*16 + b16)
    int b16 = row & 15;
    int gt = row >> 4;
    int t = gt & (T_LEN - 1);
    int g = gt >> 8;
    const unsigned short* y = Y + (size_t)row * HID;
    float a0 = b_fc[0], a1 = b_fc[1], a2 = b_fc[2];
    #pragma unroll 4
    for (int k8 = 0; k8 < 32; ++k8) {
        ushortx8 v = *(const ushortx8*)(y + k8 * 8);
        #pragma unroll
        for (int j = 0; j < 8; ++j) {
            float f = bf2f(v[j]);
            int k = k8 * 8 + j;
            a0 += f * W_fc[k];          // uniform -> scalar loads
            a1 += f * W_fc[256 + k];
            a2 += f * W_fc[512 + k];
        }
    }
    int batch = g * NBATCH + b16;
    float* o = out + ((size_t)batch * T_LEN + t) * 3;
    o[0] = a0; o[1] = a1; o[2] = a2;
}

extern "C" void kernel_launch(void* const* d_in, const int* in_sizes, int n_in,
                              void* d_out, int out_size, void* d_ws, size_t ws_size,
                              hipStream_t stream)
{
    const float* X_p      = (const float*)d_in[0];
    const float* X_f      = (const float*)d_in[1];
    const float* noise    = (const float*)d_in[2];
    const float* W_ih_enc = (const float*)d_in[3];
    const float* W_hh_enc = (const float*)d_in[4];
    const float* b_ih_enc = (const float*)d_in[5];
    const float* b_hh_enc = (const float*)d_in[6];
    const float* W_ih_dec = (const float*)d_in[7];
    const float* W_hh_dec = (const float*)d_in[8];
    const float* b_ih_dec = (const float*)d_in[9];
    const float* b_hh_dec = (const float*)d_in[10];
    const float* W_fc     = (const float*)d_in[11];
    const float* b_fc     = (const float*)d_in[12];

    // ws: [0, 512KB) fp32 encoder final h; then 67MB bf16 decoder outputs
    float* h_enc = (float*)d_ws;
    unsigned short* Yws = (unsigned short*)((char*)d_ws + (size_t)B_TOT * HID * 4);

    hipLaunchKernelGGL((gru_persistent<0>), dim3(NBLK), dim3(NTHREADS), 0, stream,
        X_p, W_hh_enc, W_ih_enc, b_ih_enc, b_hh_enc,
        (const float*)nullptr, (const float*)nullptr, h_enc,
        (unsigned short*)nullptr);

    hipLaunchKernelGGL((gru_persistent<1>), dim3(NBLK), dim3(NTHREADS), 0, stream,
        X_f, W_hh_dec, W_ih_dec, b_ih_dec, b_hh_dec,
        h_enc, noise, (float*)nullptr, Yws);

    hipLaunchKernelGGL(proj_kernel, dim3((B_TOT * T_LEN) / 256), dim3(256), 0, stream,
        Yws, W_fc, b_fc, (float*)d_out);
}

// Round 3
// 1051.640 us; speedup vs baseline: 1.6122x; 1.1887x over previous
//
#include <hip/hip_runtime.h>

// NetG: seq2seq GRU (enc GRU -> +noise -> dec GRU -> FC head)
// B=512, T=256, H=256, D=3.
//
// Persistent-RNN: 32 blocks x 512 threads (8 waves, 2/SIMD -> 256-reg cap).
// Each block owns 16 batch rows for the whole sequence.
//
// Register-file arithmetic (R2 post-mortem): W_hh bf16 = 393 KB but the CU
// regfile is 512 KB; 3 gates resident + acc + temps = ~550 KB -> spills
// (R2: VGPR_Count=128, ~4300 cyc/step of scratch reloads). So gate r lives
// in LDS as pre-swizzled per-lane A-fragments (131 KB, conflict-free
// ds_read_b128); gates z,n stay in 128 regs/lane. Nominal live ~220 <= 256.
//
// LDS (dynamic, 152 KB): Wr frags | h double-buffer (XOR-swizzled, stride
// 512 B, 16B-block j^(c&7) -> conflict-free b128) | x/bias A-frags.
// X is NOT staged: 12 B/step prefetched from global one step ahead.
// Per step: gh = W.h^T via mfma_f32_16x16x32_bf16 (8 K-steps, A from
// regs+LDS) + 9th K-step carrying [x0,x1,x2,1] folding input projection and
// biases (separate nh/nx accs honor PyTorch n = tanh(xn + r*hn)).
// h carried fp32 in registers; bf16 copy in LDS is the MFMA B operand.

#define B_TOT 512
#define T_LEN 256
#define HID 256
#define NBATCH 16
#define NTHREADS 512
#define NBLK 32

// LDS partition (units: shorts)
#define WR_OFF   0            // 16 ht x 8 k x 64 lane x 8 shorts = 65536
#define H_OFF    65536        // 2 x 16 x 256 = 8192
#define XF01_OFF 73728        // 16 ht x 16 c x 8 = 2048
#define XF23_OFF 75776        // 2048
#define SMEM_SHORTS 77824
#define SMEM_BYTES  (SMEM_SHORTS * 2)   // 155648 B <= 160 KiB

typedef __attribute__((ext_vector_type(4))) float f32x4;
typedef __attribute__((ext_vector_type(8))) short shortx8;
typedef __attribute__((ext_vector_type(4))) unsigned short ushortx4;
typedef __attribute__((ext_vector_type(8))) unsigned short ushortx8;

__device__ __forceinline__ unsigned short f2bf(float x) {
    unsigned u = __float_as_uint(x);
    u += 0x7FFF + ((u >> 16) & 1);   // RNE
    return (unsigned short)(u >> 16);
}
__device__ __forceinline__ float bf2f(unsigned short s) {
    return __uint_as_float(((unsigned)s) << 16);
}
__device__ __forceinline__ float fastrcp(float x) {
#if __has_builtin(__builtin_amdgcn_rcpf)
    return __builtin_amdgcn_rcpf(x);
#else
    return 1.0f / x;
#endif
}
__device__ __forceinline__ float sigmoid_(float x) {
    return fastrcp(1.0f + __expf(-x));
}
__device__ __forceinline__ float tanh_(float x) {
    return 2.0f * fastrcp(1.0f + __expf(-2.0f * x)) - 1.0f;
}

template<int IS_DEC>
__global__ __launch_bounds__(NTHREADS, 2) void gru_persistent(
    const float* __restrict__ X,       // [512][256][3]
    const float* __restrict__ W_hh,    // [768][256] gates r,z,n
    const float* __restrict__ W_ih,    // [768][3]
    const float* __restrict__ b_ih,    // [768]
    const float* __restrict__ b_hh,    // [768]
    const float* __restrict__ h_in,    // dec: [512][256] fp32; enc: null
    const float* __restrict__ noise,   // dec: [512][256]; enc: null
    float* __restrict__ h_out,         // enc: [512][256] fp32; dec: null
    unsigned short* __restrict__ Yout) // dec: [32][256][16][256] bf16
{
    extern __shared__ unsigned short smem[];
    unsigned short* shWr   = smem + WR_OFF;
    unsigned short* shH    = smem + H_OFF;
    unsigned short* shXf01 = smem + XF01_OFF;
    unsigned short* shXf23 = smem + XF23_OFF;

    const int tid  = threadIdx.x;
    const int g    = blockIdx.x;
    const int w    = tid >> 6;    // wave; owns hidden tiles {w, w+8}
    const int lane = tid & 63;
    const int c    = lane & 15;   // A row / B col (batch) / D col
    const int q    = lane >> 4;
    const int cx   = c & 7;

    // ---- x/bias A-frags -> LDS (per (ht,c); K-slots 0..3 of each kind) ----
    if (q == 0) {
        #pragma unroll
        for (int hti = 0; hti < 2; ++hti) {
            int ht = w + hti * 8;
            int rr = ht * 16 + c;
            int rowr = rr, rowz = 256 + rr, rown = 512 + rr;
            ushortx8 v01 = {
                f2bf(W_ih[rowr * 3 + 0]), f2bf(W_ih[rowr * 3 + 1]),
                f2bf(W_ih[rowr * 3 + 2]), f2bf(b_ih[rowr] + b_hh[rowr]),
                f2bf(W_ih[rowz * 3 + 0]), f2bf(W_ih[rowz * 3 + 1]),
                f2bf(W_ih[rowz * 3 + 2]), f2bf(b_ih[rowz] + b_hh[rowz])};
            ushortx8 v23 = {
                (unsigned short)0, (unsigned short)0, (unsigned short)0,
                f2bf(b_hh[rown]),
                f2bf(W_ih[rown * 3 + 0]), f2bf(W_ih[rown * 3 + 1]),
                f2bf(W_ih[rown * 3 + 2]), f2bf(b_ih[rown])};
            *(ushortx8*)&shXf01[(ht * 16 + c) * 8] = v01;
            *(ushortx8*)&shXf23[(ht * 16 + c) * 8] = v23;
        }
    }

    // ---- gate-r A-frags -> LDS (each wave stages the 2 tiles it reads) ----
    // frag layout: [ht][k][lane] * 8 shorts; lane-contiguous -> conflict-free
    #pragma unroll
    for (int hti = 0; hti < 2; ++hti) {
        int ht = w + hti * 8;
        int row = ht * 16 + c;                      // gate r (gbase 0)
        const float* wp = W_hh + (size_t)row * 256 + q * 8;
        #pragma unroll
        for (int k = 0; k < 8; ++k) {
            const f32x4* p = (const f32x4*)(wp + k * 32);
            f32x4 f0 = p[0];
            f32x4 f1 = p[1];
            shortx8 a;
            a[0] = (short)f2bf(f0[0]); a[1] = (short)f2bf(f0[1]);
            a[2] = (short)f2bf(f0[2]); a[3] = (short)f2bf(f0[3]);
            a[4] = (short)f2bf(f1[0]); a[5] = (short)f2bf(f1[1]);
            a[6] = (short)f2bf(f1[2]); a[7] = (short)f2bf(f1[3]);
            *(shortx8*)&shWr[((ht * 8 + k) * 64 + lane) * 8] = a;
        }
    }

    // ---- gates z,n A-frags into registers (128 regs, resident) ----
    shortx8 Wf[2][2][8];   // [hti][z|n][k]
    #pragma unroll
    for (int hti = 0; hti < 2; ++hti) {
        int ht = w + hti * 8;
        #pragma unroll
        for (int gg = 0; gg < 2; ++gg) {
            int row = (gg + 1) * 256 + ht * 16 + c;
            const float* wp = W_hh + (size_t)row * 256 + q * 8;
            #pragma unroll
            for (int k = 0; k < 8; ++k) {
                const f32x4* p = (const f32x4*)(wp + k * 32);
                f32x4 f0 = p[0];
                f32x4 f1 = p[1];
                shortx8 a;
                a[0] = (short)f2bf(f0[0]); a[1] = (short)f2bf(f0[1]);
                a[2] = (short)f2bf(f0[2]); a[3] = (short)f2bf(f0[3]);
                a[4] = (short)f2bf(f1[0]); a[5] = (short)f2bf(f1[1]);
                a[6] = (short)f2bf(f1[2]); a[7] = (short)f2bf(f1[3]);
                Wf[hti][gg][k] = a;
            }
        }
    }

    // ---- epilogue write offsets (swizzled), loop-invariant ----
    int woff[2];
    #pragma unroll
    for (int hti = 0; hti < 2; ++hti) {
        int ht = w + hti * 8;
        woff[hti] = c * HID + (((2 * ht + (q >> 1)) ^ cx) << 3) + ((q & 1) << 2);
    }

    // ---- init h: fp32 in regs; bf16 copy to buffer 0 ----
    f32x4 hold[2];
    #pragma unroll
    for (int hti = 0; hti < 2; ++hti) {
        int ht = w + hti * 8;
        int dim0 = ht * 16 + q * 4;
        f32x4 hv = {0.0f, 0.0f, 0.0f, 0.0f};
        if (IS_DEC) {
            int b = g * NBATCH + c;
            f32x4 h0 = *(const f32x4*)(h_in + (size_t)b * HID + dim0);
            f32x4 nz = *(const f32x4*)(noise + (size_t)b * HID + dim0);
            hv = h0 + nz;
        }
        hold[hti] = hv;
        ushortx4 hb16 = {f2bf(hv[0]), f2bf(hv[1]), f2bf(hv[2]), f2bf(hv[3])};
        *(ushortx4*)&shH[woff[hti]] = hb16;
    }

    // ---- x for step 0 (enc: X[:,0]; dec: zeros = right shift) ----
    float x0 = 0.0f, x1 = 0.0f, x2 = 0.0f;
    if (q == 0 && !IS_DEC) {
        const float* xp = X + (size_t)(g * NBATCH + c) * (T_LEN * 3);
        x0 = xp[0]; x1 = xp[1]; x2 = xp[2];
    }
    __syncthreads();

    const shortx8 zero8 = {0, 0, 0, 0, 0, 0, 0, 0};
    const unsigned short* ab0 = shWr + ((size_t)w * 8 * 64 + lane) * 8;
    const unsigned short* ab1 = shWr + ((size_t)(w + 8) * 8 * 64 + lane) * 8;

    // ---- recurrence ----
    for (int t = 0; t < T_LEN; ++t) {
        const unsigned short* hb = shH + (t & 1) * (NBATCH * HID);
        unsigned short* hn = shH + ((t + 1) & 1) * (NBATCH * HID);

        // decoder: stream h_t (= y_{t-1}) to global; overlaps MFMA
        if (IS_DEC && t >= 1) {
            int row = tid >> 5, jl = tid & 31;
            ushortx8 v = *(const ushortx8*)(hb + row * HID + ((jl ^ (row & 7)) << 3));
            *(ushortx8*)(Yout + (((size_t)g * T_LEN + (t - 1)) * NBATCH + row) * HID + jl * 8) = v;
        }

        // prefetch x for step t+1 (latency hidden behind MFMA)
        float xn0 = 0.0f, xn1 = 0.0f, xn2 = 0.0f;
        {
            int tsn = IS_DEC ? t : (t + 1);
            if (q == 0 && tsn < T_LEN) {
                const float* xp = X + ((size_t)(g * NBATCH + c) * T_LEN + tsn) * 3;
                xn0 = xp[0]; xn1 = xp[1]; xn2 = xp[2];
            }
        }

        f32x4 acc[2][4];  // [hti][r, z, nh, nx]
        #pragma unroll
        for (int hti = 0; hti < 2; ++hti)
            #pragma unroll
            for (int kk = 0; kk < 4; ++kk) {
                f32x4 z4 = {0.0f, 0.0f, 0.0f, 0.0f};
                acc[hti][kk] = z4;
            }

        const unsigned short* brow = hb + c * HID;
        #pragma unroll
        for (int k = 0; k < 8; ++k) {
            shortx8 bf  = *(const shortx8*)(brow + (((4 * k + q) ^ cx) << 3));
            shortx8 ar0 = *(const shortx8*)(ab0 + (size_t)k * 512);   // gate r, hti 0
            shortx8 ar1 = *(const shortx8*)(ab1 + (size_t)k * 512);   // gate r, hti 1
            acc[0][0] = __builtin_amdgcn_mfma_f32_16x16x32_bf16(ar0,         bf, acc[0][0], 0, 0, 0);
            acc[1][0] = __builtin_amdgcn_mfma_f32_16x16x32_bf16(ar1,         bf, acc[1][0], 0, 0, 0);
            acc[0][1] = __builtin_amdgcn_mfma_f32_16x16x32_bf16(Wf[0][0][k], bf, acc[0][1], 0, 0, 0);
            acc[1][1] = __builtin_amdgcn_mfma_f32_16x16x32_bf16(Wf[1][0][k], bf, acc[1][1], 0, 0, 0);
            acc[0][2] = __builtin_amdgcn_mfma_f32_16x16x32_bf16(Wf[0][1][k], bf, acc[0][2], 0, 0, 0);
            acc[1][2] = __builtin_amdgcn_mfma_f32_16x16x32_bf16(Wf[1][1][k], bf, acc[1][2], 0, 0, 0);
        }

        // 9th K-step: B rows 0..3 = [x0,x1,x2,1] (q=0 lanes), rest zero
        {
            shortx8 bx = (q == 0)
                ? shortx8{(short)f2bf(x0), (short)f2bf(x1), (short)f2bf(x2),
                          (short)(unsigned short)0x3F80, 0, 0, 0, 0}
                : zero8;
            #pragma unroll
            for (int hti = 0; hti < 2; ++hti) {
                int ht = w + hti * 8;
                ushortx8 p01 = *(const ushortx8*)&shXf01[(ht * 16 + c) * 8];
                ushortx8 p23 = *(const ushortx8*)&shXf23[(ht * 16 + c) * 8];
                shortx8 a0 = (q == 0) ? shortx8{(short)p01[0], (short)p01[1], (short)p01[2], (short)p01[3], 0, 0, 0, 0} : zero8;
                shortx8 a1 = (q == 0) ? shortx8{(short)p01[4], (short)p01[5], (short)p01[6], (short)p01[7], 0, 0, 0, 0} : zero8;
                shortx8 a2 = (q == 0) ? shortx8{(short)p23[0], (short)p23[1], (short)p23[2], (short)p23[3], 0, 0, 0, 0} : zero8;
                shortx8 a3 = (q == 0) ? shortx8{(short)p23[4], (short)p23[5], (short)p23[6], (short)p23[7], 0, 0, 0, 0} : zero8;
                acc[hti][0] = __builtin_amdgcn_mfma_f32_16x16x32_bf16(a0, bx, acc[hti][0], 0, 0, 0);
                acc[hti][1] = __builtin_amdgcn_mfma_f32_16x16x32_bf16(a1, bx, acc[hti][1], 0, 0, 0);
                acc[hti][2] = __builtin_amdgcn_mfma_f32_16x16x32_bf16(a2, bx, acc[hti][2], 0, 0, 0);
                acc[hti][3] = __builtin_amdgcn_mfma_f32_16x16x32_bf16(a3, bx, acc[hti][3], 0, 0, 0);
            }
        }

        // ---- epilogue: D[row=q*4+r][col=c]; h carried fp32 in regs ----
        #pragma unroll
        for (int hti = 0; hti < 2; ++hti) {
            f32x4 hv = hold[hti];
            f32x4 ho;
            #pragma unroll
            for (int r = 0; r < 4; ++r) {
                float rr = sigmoid_(acc[hti][0][r]);
                float zz = sigmoid_(acc[hti][1][r]);
                float nn = tanh_(acc[hti][3][r] + rr * acc[hti][2][r]);
                ho[r] = nn + zz * (hv[r] - nn);
            }
            hold[hti] = ho;
            ushortx4 hb16 = {f2bf(ho[0]), f2bf(ho[1]), f2bf(ho[2]), f2bf(ho[3])};
            *(ushortx4*)(hn + woff[hti]) = hb16;
        }
        x0 = xn0; x1 = xn1; x2 = xn2;
        __syncthreads();
    }

    if (IS_DEC) {
        // flush Y[:,255] = h_256 (buffer 0, T even)
        int row = tid >> 5, jl = tid & 31;
        ushortx8 v = *(const ushortx8*)(shH + row * HID + ((jl ^ (row & 7)) << 3));
        *(ushortx8*)(Yout + (((size_t)g * T_LEN + 255) * NBATCH + row) * HID + jl * 8) = v;
    } else {
        #pragma unroll
        for (int hti = 0; hti < 2; ++hti) {
            int ht = w + hti * 8;
            int dim0 = ht * 16 + q * 4;
            *(f32x4*)(h_out + (size_t)(g * NBATCH + c) * HID + dim0) = hold[hti];
        }
    }
}

// out[b][t][d] = sum_h Y[g][t][b16][h] * W_fc[d][h] + b_fc[d]
__global__ __launch_bounds__(256) void proj_kernel(
    const unsigned short* __restrict__ Y, const float* __restrict__ W_fc,
    const float* __restrict__ b_fc, float* __restrict__ out)
{
    int row = blockIdx.x * 256 + threadIdx.x;  // ((g*T + t)*16 + b16)
    int b16 = row & 15;
    int gt = row >> 4;
    int t = gt & (T_LEN - 1);
    int g = gt >> 8;
    const unsigned short* y = Y + (size_t)row * HID;
    float a0 = b_fc[0], a1 = b_fc[1], a2 = b_fc[2];
    #pragma unroll 4
    for (int k8 = 0; k8 < 32; ++k8) {
        ushortx8 v = *(const ushortx8*)(y + k8 * 8);
        #pragma unroll
        for (int j = 0; j < 8; ++j) {
            float f = bf2f(v[j]);
            int k = k8 * 8 + j;
            a0 += f * W_fc[k];          // uniform -> scalar loads
            a1 += f * W_fc[256 + k];
            a2 += f * W_fc[512 + k];
        }
    }
    int batch = g * NBATCH + b16;
    float* o = out + ((size_t)batch * T_LEN + t) * 3;
    o[0] = a0; o[1] = a1; o[2] = a2;
}

extern "C" void kernel_launch(void* const* d_in, const int* in_sizes, int n_in,
                              void* d_out, int out_size, void* d_ws, size_t ws_size,
                              hipStream_t stream)
{
    const float* X_p      = (const float*)d_in[0];
    const float* X_f      = (const float*)d_in[1];
    const float* noise    = (const float*)d_in[2];
    const float* W_ih_enc = (const float*)d_in[3];
    const float* W_hh_enc = (const float*)d_in[4];
    const float* b_ih_enc = (const float*)d_in[5];
    const float* b_hh_enc = (const float*)d_in[6];
    const float* W_ih_dec = (const float*)d_in[7];
    const float* W_hh_dec = (const float*)d_in[8];
    const float* b_ih_dec = (const float*)d_in[9];
    const float* b_hh_dec = (const float*)d_in[10];
    const float* W_fc     = (const float*)d_in[11];
    const float* b_fc     = (const float*)d_in[12];

    // allow >64 KiB dynamic LDS (idempotent; host-side, graph-capture safe)
    (void)hipFuncSetAttribute((const void*)&gru_persistent<0>,
                              hipFuncAttributeMaxDynamicSharedMemorySize, SMEM_BYTES);
    (void)hipFuncSetAttribute((const void*)&gru_persistent<1>,
                              hipFuncAttributeMaxDynamicSharedMemorySize, SMEM_BYTES);

    // ws: [0, 512KB) fp32 encoder final h; then 67MB bf16 decoder outputs
    float* h_enc = (float*)d_ws;
    unsigned short* Yws = (unsigned short*)((char*)d_ws + (size_t)B_TOT * HID * 4);

    hipLaunchKernelGGL((gru_persistent<0>), dim3(NBLK), dim3(NTHREADS), SMEM_BYTES, stream,
        X_p, W_hh_enc, W_ih_enc, b_ih_enc, b_hh_enc,
        (const float*)nullptr, (const float*)nullptr, h_enc,
        (unsigned short*)nullptr);

    hipLaunchKernelGGL((gru_persistent<1>), dim3(NBLK), dim3(NTHREADS), SMEM_BYTES, stream,
        X_f, W_hh_dec, W_ih_dec, b_ih_dec, b_hh_dec,
        h_enc, noise, (float*)nullptr, Yws);

    hipLaunchKernelGGL(proj_kernel, dim3((B_TOT * T_LEN) / 256), dim3(256), 0, stream,
        Yws, W_fc, b_fc, (float*)d_out);
}

// Round 4
// 941.944 us; speedup vs baseline: 1.8000x; 1.1165x over previous
//
#include <hip/hip_runtime.h>

// NetG: seq2seq GRU (enc GRU -> +noise -> dec GRU -> FC head)
// B=512, T=256, H=256, D=3.
//
// Persistent-RNN: 32 blocks x 512 threads (8 waves, 2/SIMD -> 256-reg cap).
// Each block owns 16 batch rows for the whole sequence. Structure is pinned
// at 32 CUs by the recurrence (per-step cross-CU h exchange is too slow), so
// the optimization target is per-step instruction count on the CU issue
// ports (R3 counters: MFMA 38% + VALU 57% of active-CU cycles = saturated).
//
// Weights: gates z,n bf16 A-frags resident in 128 regs/lane; gate r streams
// from LDS (pre-swizzled per-lane frags, conflict-free ds_read_b128).
// x-projection + biases ride a 9th MFMA K-step whose A-frags live in 32
// regs built ONCE (B rows >=4 are zero, so A slots k>=4 / q>=1 lanes may
// hold garbage -> no per-step masking). h carried fp32 in regs; bf16 h in
// LDS (XOR-swizzled, 16B block j^c) is the MFMA B operand. Decoder output
// h_{t+1} stores straight from epilogue regs to global (no LDS round-trip).

#define B_TOT 512
#define T_LEN 256
#define HID 256
#define NBATCH 16
#define NTHREADS 512
#define NBLK 32

// LDS partition (units: shorts)
#define WR_OFF 0              // 16 ht x 8 k x 64 lane x 8 shorts = 65536
#define H_OFF  65536          // 2 x 16 x 256 = 8192
#define SMEM_SHORTS 73728
#define SMEM_BYTES  (SMEM_SHORTS * 2)   // 147456 B <= 160 KiB

typedef __attribute__((ext_vector_type(4))) float f32x4;
typedef __attribute__((ext_vector_type(4))) int i32x4;
typedef __attribute__((ext_vector_type(8))) short shortx8;
typedef __attribute__((ext_vector_type(4))) unsigned short ushortx4;
typedef __attribute__((ext_vector_type(8))) unsigned short ushortx8;

__device__ __forceinline__ unsigned short f2bf(float x) {
    unsigned u = __float_as_uint(x);
    u += 0x7FFF + ((u >> 16) & 1);   // RNE
    return (unsigned short)(u >> 16);
}
__device__ __forceinline__ float bf2f(unsigned short s) {
    return __uint_as_float(((unsigned)s) << 16);
}
__device__ __forceinline__ float fastrcp(float x) {
#if __has_builtin(__builtin_amdgcn_rcpf)
    return __builtin_amdgcn_rcpf(x);
#else
    return 1.0f / x;
#endif
}
__device__ __forceinline__ float sigmoid_(float x) {
    return fastrcp(1.0f + __expf(-x));
}
__device__ __forceinline__ float tanh_(float x) {
    return 2.0f * fastrcp(1.0f + __expf(-2.0f * x)) - 1.0f;
}

template<int IS_DEC>
__global__ __launch_bounds__(NTHREADS, 2) void gru_persistent(
    const float* __restrict__ X,       // [512][256][3]
    const float* __restrict__ W_hh,    // [768][256] gates r,z,n
    const float* __restrict__ W_ih,    // [768][3]
    const float* __restrict__ b_ih,    // [768]
    const float* __restrict__ b_hh,    // [768]
    const float* __restrict__ h_in,    // dec: [512][256] fp32; enc: null
    const float* __restrict__ noise,   // dec: [512][256]; enc: null
    float* __restrict__ h_out,         // enc: [512][256] fp32; dec: null
    unsigned short* __restrict__ Yout) // dec: [32][256][16][256] bf16
{
    extern __shared__ unsigned short smem[];
    unsigned short* shWr = smem + WR_OFF;
    unsigned short* shH  = smem + H_OFF;

    const int tid  = threadIdx.x;
    const int g    = blockIdx.x;
    const int w    = tid >> 6;    // wave; owns hidden tiles {w, w+8}
    const int lane = tid & 63;
    const int c    = lane & 15;   // A row / B col (batch) / D col
    const int q    = lane >> 4;

    // ---- gate-r A-frags -> LDS (each wave stages the 2 tiles it reads) ----
    // layout [ht][k][lane]*8 shorts: lane-contiguous -> conflict-free b128
    #pragma unroll
    for (int hti = 0; hti < 2; ++hti) {
        int ht = w + hti * 8;
        int row = ht * 16 + c;                      // gate r (gbase 0)
        const float* wp = W_hh + (size_t)row * 256 + q * 8;
        #pragma unroll
        for (int k = 0; k < 8; ++k) {
            const f32x4* p = (const f32x4*)(wp + k * 32);
            f32x4 f0 = p[0];
            f32x4 f1 = p[1];
            shortx8 a;
            a[0] = (short)f2bf(f0[0]); a[1] = (short)f2bf(f0[1]);
            a[2] = (short)f2bf(f0[2]); a[3] = (short)f2bf(f0[3]);
            a[4] = (short)f2bf(f1[0]); a[5] = (short)f2bf(f1[1]);
            a[6] = (short)f2bf(f1[2]); a[7] = (short)f2bf(f1[3]);
            *(shortx8*)&shWr[((ht * 8 + k) * 64 + lane) * 8] = a;
        }
    }

    // ---- gates z,n A-frags into registers (128 regs, resident) ----
    shortx8 Wf[2][2][8];   // [hti][z|n][k]
    #pragma unroll
    for (int hti = 0; hti < 2; ++hti) {
        int ht = w + hti * 8;
        #pragma unroll
        for (int gg = 0; gg < 2; ++gg) {
            int row = (gg + 1) * 256 + ht * 16 + c;
            const float* wp = W_hh + (size_t)row * 256 + q * 8;
            #pragma unroll
            for (int k = 0; k < 8; ++k) {
                const f32x4* p = (const f32x4*)(wp + k * 32);
                f32x4 f0 = p[0];
                f32x4 f1 = p[1];
                shortx8 a;
                a[0] = (short)f2bf(f0[0]); a[1] = (short)f2bf(f0[1]);
                a[2] = (short)f2bf(f0[2]); a[3] = (short)f2bf(f0[3]);
                a[4] = (short)f2bf(f1[0]); a[5] = (short)f2bf(f1[1]);
                a[6] = (short)f2bf(f1[2]); a[7] = (short)f2bf(f1[3]);
                Wf[hti][gg][k] = a;
            }
        }
    }

    // ---- x/bias A-frags into 32 regs, built ONCE ----
    // Only K-slots 0..3 matter (B rows >=4 are zero); upper halves replicate.
    // All lanes compute (q-duplicates broadcast-load the same rows) so every
    // lane's regs are defined; q>=1 lanes' values multiply zero B rows.
    shortx8 ax[2][4];      // [hti][r, z, nh-bias, nx]
    #pragma unroll
    for (int hti = 0; hti < 2; ++hti) {
        int ht = w + hti * 8;
        int rr = ht * 16 + c;
        int rowr = rr, rowz = 256 + rr, rown = 512 + rr;
        short r0 = (short)f2bf(W_ih[rowr * 3 + 0]);
        short r1 = (short)f2bf(W_ih[rowr * 3 + 1]);
        short r2 = (short)f2bf(W_ih[rowr * 3 + 2]);
        short r3 = (short)f2bf(b_ih[rowr] + b_hh[rowr]);
        short z0 = (short)f2bf(W_ih[rowz * 3 + 0]);
        short z1 = (short)f2bf(W_ih[rowz * 3 + 1]);
        short z2 = (short)f2bf(W_ih[rowz * 3 + 2]);
        short z3 = (short)f2bf(b_ih[rowz] + b_hh[rowz]);
        short n0 = (short)f2bf(W_ih[rown * 3 + 0]);
        short n1 = (short)f2bf(W_ih[rown * 3 + 1]);
        short n2 = (short)f2bf(W_ih[rown * 3 + 2]);
        short n3 = (short)f2bf(b_ih[rown]);
        short nb = (short)f2bf(b_hh[rown]);
        ax[hti][0] = shortx8{r0, r1, r2, r3, r0, r1, r2, r3};
        ax[hti][1] = shortx8{z0, z1, z2, z3, z0, z1, z2, z3};
        ax[hti][2] = shortx8{0, 0, 0, nb, 0, 0, 0, nb};
        ax[hti][3] = shortx8{n0, n1, n2, n3, n0, n1, n2, n3};
    }

    // ---- epilogue write offsets (swizzle XOR full c), loop-invariant ----
    int woff[2];
    #pragma unroll
    for (int hti = 0; hti < 2; ++hti) {
        int ht = w + hti * 8;
        woff[hti] = c * HID + (((2 * ht + (q >> 1)) ^ c) << 3) + ((q & 1) << 2);
    }

    // ---- init h: fp32 in regs; bf16 copy to buffer 0 ----
    f32x4 hold[2];
    #pragma unroll
    for (int hti = 0; hti < 2; ++hti) {
        int ht = w + hti * 8;
        int dim0 = ht * 16 + q * 4;
        f32x4 hv = {0.0f, 0.0f, 0.0f, 0.0f};
        if (IS_DEC) {
            int b = g * NBATCH + c;
            f32x4 h0 = *(const f32x4*)(h_in + (size_t)b * HID + dim0);
            f32x4 nz = *(const f32x4*)(noise + (size_t)b * HID + dim0);
            hv = h0 + nz;
        }
        hold[hti] = hv;
        ushortx4 hb16 = {f2bf(hv[0]), f2bf(hv[1]), f2bf(hv[2]), f2bf(hv[3])};
        *(ushortx4*)&shH[woff[hti]] = hb16;
    }

    // ---- x for step 0 (enc: X[:,0]; dec: zeros = right shift) ----
    float x0 = 0.0f, x1 = 0.0f, x2 = 0.0f;
    if (q == 0 && !IS_DEC) {
        const float* xp = X + (size_t)(g * NBATCH + c) * (T_LEN * 3);
        x0 = xp[0]; x1 = xp[1]; x2 = xp[2];
    }
    __syncthreads();

    const unsigned short* ab0 = shWr + ((size_t)w * 8 * 64 + lane) * 8;
    const unsigned short* ab1 = shWr + ((size_t)(w + 8) * 8 * 64 + lane) * 8;

    // ---- recurrence ----
    for (int t = 0; t < T_LEN; ++t) {
        const unsigned short* hb = shH + (t & 1) * (NBATCH * HID);
        unsigned short* hn = shH + ((t + 1) & 1) * (NBATCH * HID);

        // prefetch x for step t+1 (latency hidden behind MFMA)
        float xn0 = 0.0f, xn1 = 0.0f, xn2 = 0.0f;
        {
            int tsn = IS_DEC ? t : (t + 1);
            if (q == 0 && tsn < T_LEN) {
                const float* xp = X + ((size_t)(g * NBATCH + c) * T_LEN + tsn) * 3;
                xn0 = xp[0]; xn1 = xp[1]; xn2 = xp[2];
            }
        }

        f32x4 acc[2][4];  // [hti][r, z, nh, nx]
        #pragma unroll
        for (int hti = 0; hti < 2; ++hti)
            #pragma unroll
            for (int kk = 0; kk < 4; ++kk) {
                f32x4 z4 = {0.0f, 0.0f, 0.0f, 0.0f};
                acc[hti][kk] = z4;
            }

        const unsigned short* brow = hb + c * HID;
        #pragma unroll
        for (int k = 0; k < 8; ++k) {
            shortx8 bf  = *(const shortx8*)(brow + (((4 * k + q) ^ c) << 3));
            shortx8 ar0 = *(const shortx8*)(ab0 + (size_t)k * 512);   // gate r, hti 0
            shortx8 ar1 = *(const shortx8*)(ab1 + (size_t)k * 512);   // gate r, hti 1
            acc[0][0] = __builtin_amdgcn_mfma_f32_16x16x32_bf16(ar0,         bf, acc[0][0], 0, 0, 0);
            acc[1][0] = __builtin_amdgcn_mfma_f32_16x16x32_bf16(ar1,         bf, acc[1][0], 0, 0, 0);
            acc[0][1] = __builtin_amdgcn_mfma_f32_16x16x32_bf16(Wf[0][0][k], bf, acc[0][1], 0, 0, 0);
            acc[1][1] = __builtin_amdgcn_mfma_f32_16x16x32_bf16(Wf[1][0][k], bf, acc[1][1], 0, 0, 0);
            acc[0][2] = __builtin_amdgcn_mfma_f32_16x16x32_bf16(Wf[0][1][k], bf, acc[0][2], 0, 0, 0);
            acc[1][2] = __builtin_amdgcn_mfma_f32_16x16x32_bf16(Wf[1][1][k], bf, acc[1][2], 0, 0, 0);
        }

        // 9th K-step: B rows 0..3 = [x0,x1,x2,1] (q=0 lanes), rows 4..31 zero
        {
            unsigned bxlo = 0u, bxhi = 0u;
            if (q == 0) {
                bxlo = (unsigned)f2bf(x0) | ((unsigned)f2bf(x1) << 16);
                bxhi = (unsigned)f2bf(x2) | 0x3F800000u;   // 1.0bf16 in high half
            }
            i32x4 bi = {(int)bxlo, (int)bxhi, 0, 0};
            shortx8 bx = *(shortx8*)&bi;
            #pragma unroll
            for (int hti = 0; hti < 2; ++hti) {
                acc[hti][0] = __builtin_amdgcn_mfma_f32_16x16x32_bf16(ax[hti][0], bx, acc[hti][0], 0, 0, 0);
                acc[hti][1] = __builtin_amdgcn_mfma_f32_16x16x32_bf16(ax[hti][1], bx, acc[hti][1], 0, 0, 0);
                acc[hti][2] = __builtin_amdgcn_mfma_f32_16x16x32_bf16(ax[hti][2], bx, acc[hti][2], 0, 0, 0);
                acc[hti][3] = __builtin_amdgcn_mfma_f32_16x16x32_bf16(ax[hti][3], bx, acc[hti][3], 0, 0, 0);
            }
        }

        // ---- epilogue: D[row=q*4+r][col=c]; h carried fp32 in regs ----
        #pragma unroll
        for (int hti = 0; hti < 2; ++hti) {
            int ht = w + hti * 8;
            f32x4 hv = hold[hti];
            f32x4 ho;
            #pragma unroll
            for (int r = 0; r < 4; ++r) {
                float rr = sigmoid_(acc[hti][0][r]);
                float zz = sigmoid_(acc[hti][1][r]);
                float nn = tanh_(acc[hti][3][r] + rr * acc[hti][2][r]);
                ho[r] = nn + zz * (hv[r] - nn);
            }
            hold[hti] = ho;
            ushortx4 hb16 = {f2bf(ho[0]), f2bf(ho[1]), f2bf(ho[2]), f2bf(ho[3])};
            *(ushortx4*)(hn + woff[hti]) = hb16;
            if (IS_DEC) {
                // y_t = h_{t+1}: store straight from epilogue regs
                unsigned short* yp = Yout +
                    (((size_t)g * T_LEN + t) * NBATCH + c) * HID + ht * 16 + q * 4;
                *(ushortx4*)yp = hb16;
            }
        }
        x0 = xn0; x1 = xn1; x2 = xn2;
        __syncthreads();
    }

    if (!IS_DEC) {
        #pragma unroll
        for (int hti = 0; hti < 2; ++hti) {
            int ht = w + hti * 8;
            int dim0 = ht * 16 + q * 4;
            *(f32x4*)(h_out + (size_t)(g * NBATCH + c) * HID + dim0) = hold[hti];
        }
    }
}

// out[b][t][d] = sum_h Y[g][t][b16][h] * W_fc[d][h] + b_fc[d]
__global__ __launch_bounds__(256) void proj_kernel(
    const unsigned short* __restrict__ Y, const float* __restrict__ W_fc,
    const float* __restrict__ b_fc, float* __restrict__ out)
{
    int row = blockIdx.x * 256 + threadIdx.x;  // ((g*T + t)*16 + b16)
    int b16 = row & 15;
    int gt = row >> 4;
    int t = gt & (T_LEN - 1);
    int g = gt >> 8;
    const unsigned short* y = Y + (size_t)row * HID;
    float a0 = b_fc[0], a1 = b_fc[1], a2 = b_fc[2];
    #pragma unroll 4
    for (int k8 = 0; k8 < 32; ++k8) {
        ushortx8 v = *(const ushortx8*)(y + k8 * 8);
        #pragma unroll
        for (int j = 0; j < 8; ++j) {
            float f = bf2f(v[j]);
            int k = k8 * 8 + j;
            a0 += f * W_fc[k];          // uniform -> scalar loads
            a1 += f * W_fc[256 + k];
            a2 += f * W_fc[512 + k];
        }
    }
    int batch = g * NBATCH + b16;
    float* o = out + ((size_t)batch * T_LEN + t) * 3;
    o[0] = a0; o[1] = a1; o[2] = a2;
}

extern "C" void kernel_launch(void* const* d_in, const int* in_sizes, int n_in,
                              void* d_out, int out_size, void* d_ws, size_t ws_size,
                              hipStream_t stream)
{
    const float* X_p      = (const float*)d_in[0];
    const float* X_f      = (const float*)d_in[1];
    const float* noise    = (const float*)d_in[2];
    const float* W_ih_enc = (const float*)d_in[3];
    const float* W_hh_enc = (const float*)d_in[4];
    const float* b_ih_enc = (const float*)d_in[5];
    const float* b_hh_enc = (const float*)d_in[6];
    const float* W_ih_dec = (const float*)d_in[7];
    const float* W_hh_dec = (const float*)d_in[8];
    const float* b_ih_dec = (const float*)d_in[9];
    const float* b_hh_dec = (const float*)d_in[10];
    const float* W_fc     = (const float*)d_in[11];
    const float* b_fc     = (const float*)d_in[12];

    // allow >64 KiB dynamic LDS (idempotent; host-side, graph-capture safe)
    (void)hipFuncSetAttribute((const void*)&gru_persistent<0>,
                              hipFuncAttributeMaxDynamicSharedMemorySize, SMEM_BYTES);
    (void)hipFuncSetAttribute((const void*)&gru_persistent<1>,
                              hipFuncAttributeMaxDynamicSharedMemorySize, SMEM_BYTES);

    // ws: [0, 512KB) fp32 encoder final h; then 67MB bf16 decoder outputs
    float* h_enc = (float*)d_ws;
    unsigned short* Yws = (unsigned short*)((char*)d_ws + (size_t)B_TOT * HID * 4);

    hipLaunchKernelGGL((gru_persistent<0>), dim3(NBLK), dim3(NTHREADS), SMEM_BYTES, stream,
        X_p, W_hh_enc, W_ih_enc, b_ih_enc, b_hh_enc,
        (const float*)nullptr, (const float*)nullptr, h_enc,
        (unsigned short*)nullptr);

    hipLaunchKernelGGL((gru_persistent<1>), dim3(NBLK), dim3(NTHREADS), SMEM_BYTES, stream,
        X_f, W_hh_dec, W_ih_dec, b_ih_dec, b_hh_dec,
        h_enc, noise, (float*)nullptr, Yws);

    hipLaunchKernelGGL(proj_kernel, dim3((B_TOT * T_LEN) / 256), dim3(256), 0, stream,
        Yws, W_fc, b_fc, (float*)d_out);
}